// Round 1
// baseline (93.741 us; speedup 1.0000x reference)
//
#include <hip/hip_runtime.h>

#define N_SAMPLES 128
#define EPS 1e-10f

// One 64-lane wave per ray. Lane i owns samples 2i and 2i+1.
// weights[s] = alpha[s] * prod_{j<s}(1 - alpha[j] + EPS)   (shift-by-1 transmittance)
__global__ __launch_bounds__(256) void VolumeRenderer_14336600834233_kernel(
    const float* __restrict__ alpha,
    const float* __restrict__ rgbs,
    float* __restrict__ out,
    int n_rays)
{
    const int wavesPerBlock = blockDim.x >> 6;
    const int ray  = blockIdx.x * wavesPerBlock + (threadIdx.x >> 6);
    const int lane = threadIdx.x & 63;
    if (ray >= n_rays) return;

    // ---- load 2 alpha samples (coalesced float2: 512 B per wave) ----
    const float2* a2 = (const float2*)alpha;
    const float2 a = a2[(size_t)ray * (N_SAMPLES / 2) + lane];
    const float f0 = 1.0f - a.x + EPS;
    const float f1 = 1.0f - a.y + EPS;
    const float p  = f0 * f1;              // lane-local product of its 2 factors

    // ---- inclusive product-scan across 64 lanes (6 shfl_up steps) ----
    float incl = p;
    #pragma unroll
    for (int off = 1; off < 64; off <<= 1) {
        float v = __shfl_up(incl, off, 64);
        if (lane >= off) incl *= v;
    }
    // exclusive scan: product of all pairs in lanes < i
    float excl = __shfl_up(incl, 1, 64);
    if (lane == 0) excl = 1.0f;

    // transmittance (shifted) at sample 2i is excl; at 2i+1 it's excl*f0
    const float w0 = a.x * excl;
    const float w1 = a.y * excl * f0;

    // ---- load rgb for both samples: 3 x float2 per lane (1536 B contiguous per wave) ----
    const float2* rg = (const float2*)rgbs;
    const size_t base = (size_t)ray * (N_SAMPLES * 3 / 2) + 3 * lane;
    const float2 v0 = rg[base + 0];   // (r0, g0)
    const float2 v1 = rg[base + 1];   // (b0, r1)
    const float2 v2 = rg[base + 2];   // (g1, b1)

    float cr = fmaf(w0, v0.x, w1 * v1.y);
    float cg = fmaf(w0, v0.y, w1 * v2.x);
    float cb = fmaf(w0, v1.x, w1 * v2.y);

    // ---- wave sum-reduction (6 shfl_xor steps) ----
    #pragma unroll
    for (int off = 32; off; off >>= 1) {
        cr += __shfl_xor(cr, off, 64);
        cg += __shfl_xor(cg, off, 64);
        cb += __shfl_xor(cb, off, 64);
    }

    if (lane == 0) {
        float* o = out + (size_t)ray * 3;
        o[0] = cr;
        o[1] = cg;
        o[2] = cb;
    }
}

extern "C" void kernel_launch(void* const* d_in, const int* in_sizes, int n_in,
                              void* d_out, int out_size, void* d_ws, size_t ws_size,
                              hipStream_t stream) {
    const float* alpha = (const float*)d_in[0];
    const float* rgbs  = (const float*)d_in[1];
    float* out = (float*)d_out;

    const int n_rays = in_sizes[0] / N_SAMPLES;   // 262144

    const int block = 256;                        // 4 waves -> 4 rays per block
    const int waves_per_block = block / 64;
    const int grid = (n_rays + waves_per_block - 1) / waves_per_block;

    VolumeRenderer_14336600834233_kernel<<<grid, block, 0, stream>>>(
        alpha, rgbs, out, n_rays);
}